// Round 2
// baseline (831.808 us; speedup 1.0000x reference)
//
#include <hip/hip_runtime.h>
#include <hip/hip_bf16.h>
#include <stdint.h>

#define NN 50000
#define NE 800000
#define CC 96
#define NL 3

typedef __bf16 bf16x8 __attribute__((ext_vector_type(8)));
typedef float f32x4 __attribute__((ext_vector_type(4)));

__device__ __forceinline__ uint16_t f2bf(float f){
  uint32_t u = __builtin_bit_cast(uint32_t, f);
  uint32_t r = (u + 0x7fffu + ((u >> 16) & 1u)) >> 16;
  return (uint16_t)r;
}
__device__ __forceinline__ float bf2f(uint16_t h){
  uint32_t u = ((uint32_t)h) << 16;
  return __builtin_bit_cast(float, u);
}
// split f32 -> (hi, lo) bf16 pair; hi+lo reproduces f ~17 mantissa bits
__device__ __forceinline__ void split_bf(float f, uint16_t& hi, uint16_t& lo){
  hi = f2bf(f);
  lo = f2bf(f - bf2f(hi));
}

__global__ void k_zero_counts(int* counts){
  int i = blockIdx.x*256 + threadIdx.x;
  if(i < NN) counts[i] = 0;
}

__global__ void k_hist(const int* __restrict__ dstv, int* __restrict__ counts){
  int e = blockIdx.x*256 + threadIdx.x;
  if(e < NE) atomicAdd(&counts[dstv[e]], 1);
}

// single-block scan over NN counts -> exclusive offsets + cursor copy
__global__ void k_scan(const int* __restrict__ counts, int* __restrict__ offsets,
                       int* __restrict__ cursor){
  __shared__ int sh[1024];
  __shared__ int carry_sh;
  int t = threadIdx.x;
  if(t==0) carry_sh = 0;
  __syncthreads();
  for(int base=0; base<NN; base+=1024){
    int i = base + t;
    int v = (i<NN)? counts[i] : 0;
    sh[t] = v;
    __syncthreads();
    for(int d=1; d<1024; d<<=1){
      int add = (t>=d)? sh[t-d] : 0;
      __syncthreads();
      sh[t] += add;
      __syncthreads();
    }
    int incl = sh[t];
    int carry = carry_sh;
    if(i<NN){ int o = carry + incl - v; offsets[i] = o; cursor[i] = o; }
    __syncthreads();
    if(t==1023) carry_sh = carry + incl;
    __syncthreads();
  }
  if(t==0) offsets[NN] = carry_sh;
}

__global__ void k_fill(const int* __restrict__ srcv, const int* __restrict__ dstv,
                       int* __restrict__ cursor, int* __restrict__ ssrc){
  int e = blockIdx.x*256 + threadIdx.x;
  if(e < NE){
    int d = dstv[e];
    int pos = atomicAdd(&cursor[d], 1);
    ssrc[pos] = srcv[e];
  }
}

// f32 -> hi/lo bf16 split (for layer-0 x)
__global__ void k_split(const float4* __restrict__ x, ushort4* __restrict__ xh,
                        ushort4* __restrict__ xl, int n4){
  int i = blockIdx.x*256 + threadIdx.x;
  if(i<n4){
    float4 v = x[i];
    ushort4 h, l;
    split_bf(v.x, h.x, l.x); split_bf(v.y, h.y, l.y);
    split_bf(v.z, h.z, l.z); split_bf(v.w, h.w, l.w);
    xh[i] = h; xl[i] = l;
  }
}

// Pack Wc[l] = weight[l] @ w_ih^T into [l][tile18][n16][k96] hi/lo bf16,
// and w_hh^T into [tile18][n16][k96] hi/lo bf16.
__global__ void k_pack_w(const float* __restrict__ weight, const float* __restrict__ w_ih,
                         const float* __restrict__ w_hh,
                         uint16_t* __restrict__ wch, uint16_t* __restrict__ wcl,
                         uint16_t* __restrict__ whhh, uint16_t* __restrict__ whhl){
  int idx = blockIdx.x*256 + threadIdx.x;
  const int TOT1 = NL*18*16*CC;   // 82944
  const int TOT2 = 18*16*CC;      // 27648
  if(idx < TOT1){
    int k = idx % CC;
    int n = (idx / CC) & 15;
    int t = (idx / (CC*16)) % 18;
    int l = idx / (CC*16*18);
    int j = t*16 + n;             // output column in [0,288)
    const float* wr = weight + (size_t)(l*CC + k)*CC;
    const float* ir = w_ih + (size_t)j*CC;
    float acc = 0.f;
    for(int k2=0;k2<CC;k2++) acc += wr[k2]*ir[k2];
    uint16_t h, lo; split_bf(acc, h, lo);
    wch[idx] = h; wcl[idx] = lo;
  } else {
    int idx2 = idx - TOT1;
    if(idx2 < TOT2){
      int k = idx2 % CC;
      int n = (idx2 / CC) & 15;
      int t = idx2 / (CC*16);
      int j = t*16 + n;
      uint16_t h, lo; split_bf(w_hh[(size_t)j*CC + k], h, lo);
      whhh[idx2] = h; whhl[idx2] = lo;
    }
  }
}

// CSR aggregation in f32: s[n][c] = sum_{edges into n} xf[src][c]; write hi/lo split.
__global__ void k_aggregate(const float* __restrict__ xf, const int* __restrict__ offsets,
                            const int* __restrict__ ssrc,
                            uint16_t* __restrict__ sh_out, uint16_t* __restrict__ sl_out){
  int tid = blockIdx.x*256 + threadIdx.x;
  if(tid >= NN*CC) return;
  int n = tid / CC;
  int c = tid - n*CC;
  int o0 = offsets[n], o1 = offsets[n+1];
  float acc = 0.f;
  for(int j=o0;j<o1;j++){
    int s = ssrc[j];
    acc += xf[(size_t)s*CC + c];
  }
  uint16_t h, l; split_bf(acc, h, l);
  sh_out[tid] = h; sl_out[tid] = l;
}

#define MFMA(A,B,C) __builtin_amdgcn_mfma_f32_16x16x32_bf16(A,B,C,0,0,0)

// Fused dual-GEMM (gi = s@Wc, gh = x@WhhT) in split-bf16 (3 MFMA/gate/K-step)
// + GRU epilogue. 1 wave = 16 nodes x 16 channels.
__global__ __launch_bounds__(256) void k_gru(
    const uint16_t* __restrict__ s_h, const uint16_t* __restrict__ s_l,
    const uint16_t* __restrict__ x_h, const uint16_t* __restrict__ x_l,
    const float* __restrict__ xf,
    const uint16_t* __restrict__ wch_l, const uint16_t* __restrict__ wcl_l,
    const uint16_t* __restrict__ whhh, const uint16_t* __restrict__ whhl,
    const float* __restrict__ b_ih, const float* __restrict__ b_hh,
    float* __restrict__ out_f, uint16_t* __restrict__ out_h, uint16_t* __restrict__ out_l)
{
  int wave = threadIdx.x >> 6;
  int lane = threadIdx.x & 63;
  int mtile = blockIdx.x*4 + wave;
  if(mtile >= NN/16) return;          // 3125 M-tiles exactly
  int tcol = blockIdx.y;              // 0..5 (channel tile)
  int nidx = lane & 15;
  int quad = lane >> 4;

  size_t arow = (size_t)(mtile*16 + nidx)*CC;
  const uint16_t* sAh = s_h + arow;
  const uint16_t* sAl = s_l + arow;
  const uint16_t* xAh = x_h + arow;
  const uint16_t* xAl = x_l + arow;
  size_t bir = (size_t)(tcol     )*16*CC + nidx*CC;
  size_t biz = (size_t)(tcol + 6 )*16*CC + nidx*CC;
  size_t bin = (size_t)(tcol + 12)*16*CC + nidx*CC;

  f32x4 air = {0.f,0.f,0.f,0.f}, aiz = {0.f,0.f,0.f,0.f}, ain = {0.f,0.f,0.f,0.f};
  f32x4 ahr = {0.f,0.f,0.f,0.f}, ahz = {0.f,0.f,0.f,0.f}, ahn = {0.f,0.f,0.f,0.f};

  #pragma unroll
  for(int ks=0; ks<3; ks++){
    int ko = ks*32 + quad*8;
    bf16x8 ash = *reinterpret_cast<const bf16x8*>(sAh + ko);
    bf16x8 asl = *reinterpret_cast<const bf16x8*>(sAl + ko);
    bf16x8 axh = *reinterpret_cast<const bf16x8*>(xAh + ko);
    bf16x8 axl = *reinterpret_cast<const bf16x8*>(xAl + ko);
    bf16x8 bh, bl;

    bh = *reinterpret_cast<const bf16x8*>(wch_l + bir + ko);
    bl = *reinterpret_cast<const bf16x8*>(wcl_l + bir + ko);
    air = MFMA(ash, bh, air); air = MFMA(asl, bh, air); air = MFMA(ash, bl, air);
    bh = *reinterpret_cast<const bf16x8*>(wch_l + biz + ko);
    bl = *reinterpret_cast<const bf16x8*>(wcl_l + biz + ko);
    aiz = MFMA(ash, bh, aiz); aiz = MFMA(asl, bh, aiz); aiz = MFMA(ash, bl, aiz);
    bh = *reinterpret_cast<const bf16x8*>(wch_l + bin + ko);
    bl = *reinterpret_cast<const bf16x8*>(wcl_l + bin + ko);
    ain = MFMA(ash, bh, ain); ain = MFMA(asl, bh, ain); ain = MFMA(ash, bl, ain);

    bh = *reinterpret_cast<const bf16x8*>(whhh + bir + ko);
    bl = *reinterpret_cast<const bf16x8*>(whhl + bir + ko);
    ahr = MFMA(axh, bh, ahr); ahr = MFMA(axl, bh, ahr); ahr = MFMA(axh, bl, ahr);
    bh = *reinterpret_cast<const bf16x8*>(whhh + biz + ko);
    bl = *reinterpret_cast<const bf16x8*>(whhl + biz + ko);
    ahz = MFMA(axh, bh, ahz); ahz = MFMA(axl, bh, ahz); ahz = MFMA(axh, bl, ahz);
    bh = *reinterpret_cast<const bf16x8*>(whhh + bin + ko);
    bl = *reinterpret_cast<const bf16x8*>(whhl + bin + ko);
    ahn = MFMA(axh, bh, ahn); ahn = MFMA(axl, bh, ahn); ahn = MFMA(axh, bl, ahn);
  }

  int c = tcol*16 + nidx;
  float bir_ = b_ih[c], biz_ = b_ih[CC+c], bin_ = b_ih[2*CC+c];
  float bhr_ = b_hh[c], bhz_ = b_hh[CC+c], bhn_ = b_hh[2*CC+c];

  #pragma unroll
  for(int r=0;r<4;r++){
    int node = mtile*16 + quad*4 + r;   // C/D: row = quad*4 + reg, col = lane&15
    float ir  = air[r] + bir_;
    float iz  = aiz[r] + biz_;
    float in_ = ain[r] + bin_;
    float hr  = ahr[r] + bhr_;
    float hz  = ahz[r] + bhz_;
    float hn  = ahn[r] + bhn_;
    float rg = 1.f/(1.f + __expf(-(ir+hr)));
    float zg = 1.f/(1.f + __expf(-(iz+hz)));
    float nv = in_ + rg*hn;
    float av = fminf(fabsf(nv), 15.f);
    float e2 = __expf(2.f*av);
    float tg = 1.f - 2.f/(e2 + 1.f);
    tg = (nv < 0.f)? -tg : tg;
    float hp = xf[(size_t)node*CC + c];
    float h = (1.f - zg)*tg + zg*hp;
    size_t oi = (size_t)node*CC + c;
    out_f[oi] = h;
    if(out_h){
      uint16_t hh, hl; split_bf(h, hh, hl);
      out_h[oi] = hh; out_l[oi] = hl;
    }
  }
}

extern "C" void kernel_launch(void* const* d_in, const int* in_sizes, int n_in,
                              void* d_out, int out_size, void* d_ws, size_t ws_size,
                              hipStream_t stream){
  const float* x0     = (const float*)d_in[0];
  const int*   ei     = (const int*)d_in[1];
  const float* weight = (const float*)d_in[2];
  const float* w_ih   = (const float*)d_in[3];
  const float* w_hh   = (const float*)d_in[4];
  const float* b_ih   = (const float*)d_in[5];
  const float* b_hh   = (const float*)d_in[6];
  float* out = (float*)d_out;

  const int* srcv = ei;        // edge_index[0]
  const int* dstv = ei + NE;   // edge_index[1]

  char* ws = (char*)d_ws;
  size_t off = 0;
  auto carve = [&](size_t bytes)->char*{
    char* p = ws + off;
    off += (bytes + 255) & ~(size_t)255;
    return p;
  };
  int* counts   = (int*)carve((size_t)NN*4);
  int* offsets  = (int*)carve((size_t)(NN+1)*4);
  int* cursor   = (int*)carve((size_t)NN*4);
  int* ssrc     = (int*)carve((size_t)NE*4);
  uint16_t* s_h = (uint16_t*)carve((size_t)NN*CC*2);
  uint16_t* s_l = (uint16_t*)carve((size_t)NN*CC*2);
  uint16_t* xh0 = (uint16_t*)carve((size_t)NN*CC*2);
  uint16_t* xl0 = (uint16_t*)carve((size_t)NN*CC*2);
  uint16_t* xh1 = (uint16_t*)carve((size_t)NN*CC*2);
  uint16_t* xl1 = (uint16_t*)carve((size_t)NN*CC*2);
  float* xfA    = (float*)carve((size_t)NN*CC*4);     // f32 x after layer0/1 (in-place safe)
  uint16_t* wch  = (uint16_t*)carve((size_t)NL*18*16*CC*2);
  uint16_t* wcl  = (uint16_t*)carve((size_t)NL*18*16*CC*2);
  uint16_t* whhh = (uint16_t*)carve((size_t)18*16*CC*2);
  uint16_t* whhl = (uint16_t*)carve((size_t)18*16*CC*2);

  // CSR build (once — edge structure shared by all 3 layers)
  k_zero_counts<<<(NN+255)/256, 256, 0, stream>>>(counts);
  k_hist<<<(NE+255)/256, 256, 0, stream>>>(dstv, counts);
  k_scan<<<1, 1024, 0, stream>>>(counts, offsets, cursor);
  k_fill<<<(NE+255)/256, 256, 0, stream>>>(srcv, dstv, cursor, ssrc);

  // x0 -> hi/lo split; fold Wc = W @ w_ih^T and pack weights (hi/lo) once
  k_split<<<((NN*CC/4)+255)/256, 256, 0, stream>>>((const float4*)x0, (ushort4*)xh0, (ushort4*)xl0, NN*CC/4);
  k_pack_w<<<((NL*18*16*CC + 18*16*CC)+255)/256, 256, 0, stream>>>(weight, w_ih, w_hh, wch, wcl, whhh, whhl);

  const float* xf_cur = x0;
  uint16_t *xh_cur=xh0, *xl_cur=xl0, *xh_nxt=xh1, *xl_nxt=xl1;
  for(int l=0; l<NL; l++){
    k_aggregate<<<((NN*CC)+255)/256, 256, 0, stream>>>(xf_cur, offsets, ssrc, s_h, s_l);
    float* out_f = (l==NL-1) ? out : xfA;   // layer1 runs in-place on xfA (safe: 1:1 thread read->write)
    uint16_t* oh = (l==NL-1) ? nullptr : xh_nxt;
    uint16_t* ol = (l==NL-1) ? nullptr : xl_nxt;
    dim3 grid((NN/16 + 3)/4, 6);
    k_gru<<<grid, 256, 0, stream>>>(s_h, s_l, xh_cur, xl_cur, xf_cur,
                                    wch + (size_t)l*18*16*CC, wcl + (size_t)l*18*16*CC,
                                    whhh, whhl, b_ih, b_hh, out_f, oh, ol);
    xf_cur = out_f;
    uint16_t* t;
    t = xh_cur; xh_cur = xh_nxt; xh_nxt = t;
    t = xl_cur; xl_cur = xl_nxt; xl_nxt = t;
  }
}

// Round 3
// 551.375 us; speedup vs baseline: 1.5086x; 1.5086x over previous
//
#include <hip/hip_runtime.h>
#include <hip/hip_bf16.h>
#include <stdint.h>

#define NN 50000
#define NE 800000
#define CC 96
#define NL 3

typedef __bf16 bf16x8 __attribute__((ext_vector_type(8)));
typedef float f32x4 __attribute__((ext_vector_type(4)));

__device__ __forceinline__ uint16_t f2bf(float f){
  uint32_t u = __builtin_bit_cast(uint32_t, f);
  uint32_t r = (u + 0x7fffu + ((u >> 16) & 1u)) >> 16;
  return (uint16_t)r;
}
__device__ __forceinline__ float bf2f(uint16_t h){
  uint32_t u = ((uint32_t)h) << 16;
  return __builtin_bit_cast(float, u);
}
// split f32 -> (hi, lo) bf16 pair; hi+lo reproduces f ~17 mantissa bits
__device__ __forceinline__ void split_bf(float f, uint16_t& hi, uint16_t& lo){
  hi = f2bf(f);
  lo = f2bf(f - bf2f(hi));
}

__global__ void k_zero(int* counts, int* gcur){
  int i = blockIdx.x*256 + threadIdx.x;
  if(i < NN) counts[i] = 0;
  if(i == 0) *gcur = 0;
}

__global__ void k_hist(const int* __restrict__ dstv, int* __restrict__ counts){
  int e = blockIdx.x*256 + threadIdx.x;
  if(e < NE) atomicAdd(&counts[dstv[e]], 1);
}

// Scan-free bucket assignment: CSR bucket ORDER is arbitrary — wave-prefix-scan
// counts, one atomicAdd on a global cursor per wave grabs the bucket range.
__global__ void k_assign(const int* __restrict__ counts, int* __restrict__ offsets,
                         int* __restrict__ cursor, int* __restrict__ gcur){
  int i = blockIdx.x*256 + threadIdx.x;
  int lane = threadIdx.x & 63;
  int v = (i < NN) ? counts[i] : 0;
  int sum = v;                          // inclusive wave scan
  #pragma unroll
  for(int d=1; d<64; d<<=1){
    int t = __shfl_up(sum, d, 64);
    if(lane >= d) sum += t;
  }
  int total = __shfl(sum, 63, 64);
  int base = 0;
  if(lane == 63) base = atomicAdd(gcur, total);
  base = __shfl(base, 63, 64);
  int off = base + sum - v;
  if(i < NN){ offsets[i] = off; cursor[i] = off; }
}

__global__ void k_fill(const int* __restrict__ srcv, const int* __restrict__ dstv,
                       int* __restrict__ cursor, int* __restrict__ ssrc){
  int e = blockIdx.x*256 + threadIdx.x;
  if(e < NE){
    int d = dstv[e];
    int pos = atomicAdd(&cursor[d], 1);
    ssrc[pos] = srcv[e];
  }
}

// f32 -> hi/lo bf16 split (for layer-0 x)
__global__ void k_split(const float4* __restrict__ x, ushort4* __restrict__ xh,
                        ushort4* __restrict__ xl, int n4){
  int i = blockIdx.x*256 + threadIdx.x;
  if(i<n4){
    float4 v = x[i];
    ushort4 h, l;
    split_bf(v.x, h.x, l.x); split_bf(v.y, h.y, l.y);
    split_bf(v.z, h.z, l.z); split_bf(v.w, h.w, l.w);
    xh[i] = h; xl[i] = l;
  }
}

// Pack Wc[l] = weight[l] @ w_ih^T into [l][tile18][n16][k96] hi/lo bf16,
// and w_hh^T into [tile18][n16][k96] hi/lo bf16. float4 dot (rows are 384B-aligned).
__global__ void k_pack_w(const float* __restrict__ weight, const float* __restrict__ w_ih,
                         const float* __restrict__ w_hh,
                         uint16_t* __restrict__ wch, uint16_t* __restrict__ wcl,
                         uint16_t* __restrict__ whhh, uint16_t* __restrict__ whhl){
  int idx = blockIdx.x*256 + threadIdx.x;
  const int TOT1 = NL*18*16*CC;   // 82944
  const int TOT2 = 18*16*CC;      // 27648
  if(idx < TOT1){
    int k = idx % CC;
    int n = (idx / CC) & 15;
    int t = (idx / (CC*16)) % 18;
    int l = idx / (CC*16*18);
    int j = t*16 + n;             // output column in [0,288)
    const float4* wr = (const float4*)(weight + (size_t)(l*CC + k)*CC);
    const float4* ir = (const float4*)(w_ih + (size_t)j*CC);
    float acc = 0.f;
    #pragma unroll 4
    for(int k2=0;k2<CC/4;k2++){
      float4 a = wr[k2], b = ir[k2];
      acc += a.x*b.x + a.y*b.y + a.z*b.z + a.w*b.w;
    }
    uint16_t h, lo; split_bf(acc, h, lo);
    wch[idx] = h; wcl[idx] = lo;
  } else {
    int idx2 = idx - TOT1;
    if(idx2 < TOT2){
      int k = idx2 % CC;
      int n = (idx2 / CC) & 15;
      int t = idx2 / (CC*16);
      int j = t*16 + n;
      uint16_t h, lo; split_bf(w_hh[(size_t)j*CC + k], h, lo);
      whhh[idx2] = h; whhl[idx2] = lo;
    }
  }
}

// CSR aggregation, vectorized: thread = (node, c4) with c4 in [0,24); float4
// gathers with 4-wide ssrc prefetch for memory-level parallelism.
__global__ void k_aggregate(const float* __restrict__ xf, const int* __restrict__ offsets,
                            const int* __restrict__ counts, const int* __restrict__ ssrc,
                            uint16_t* __restrict__ sh_out, uint16_t* __restrict__ sl_out){
  int tid = blockIdx.x*256 + threadIdx.x;
  if(tid >= NN*(CC/4)) return;
  int n = tid / (CC/4);
  int c4 = tid - n*(CC/4);
  int o0 = offsets[n];
  int o1 = o0 + counts[n];
  const float4* xf4 = (const float4*)xf;
  float ax=0.f, ay=0.f, az=0.f, aw=0.f;
  int j = o0;
  for(; j+4 <= o1; j+=4){
    int s0 = ssrc[j], s1 = ssrc[j+1], s2 = ssrc[j+2], s3 = ssrc[j+3];
    float4 v0 = xf4[(size_t)s0*(CC/4) + c4];
    float4 v1 = xf4[(size_t)s1*(CC/4) + c4];
    float4 v2 = xf4[(size_t)s2*(CC/4) + c4];
    float4 v3 = xf4[(size_t)s3*(CC/4) + c4];
    ax += v0.x+v1.x+v2.x+v3.x;
    ay += v0.y+v1.y+v2.y+v3.y;
    az += v0.z+v1.z+v2.z+v3.z;
    aw += v0.w+v1.w+v2.w+v3.w;
  }
  for(; j < o1; j++){
    float4 v = xf4[(size_t)ssrc[j]*(CC/4) + c4];
    ax += v.x; ay += v.y; az += v.z; aw += v.w;
  }
  ushort4 h, l;
  split_bf(ax, h.x, l.x); split_bf(ay, h.y, l.y);
  split_bf(az, h.z, l.z); split_bf(aw, h.w, l.w);
  ((ushort4*)sh_out)[tid] = h;
  ((ushort4*)sl_out)[tid] = l;
}

#define MFMA(A,B,C) __builtin_amdgcn_mfma_f32_16x16x32_bf16(A,B,C,0,0,0)

// Fused dual-GEMM (gi = s@Wc, gh = x@WhhT) in split-bf16 (3 MFMA/gate/K-step)
// + GRU epilogue. 1 wave = 16 nodes x 16 channels.
__global__ __launch_bounds__(256) void k_gru(
    const uint16_t* __restrict__ s_h, const uint16_t* __restrict__ s_l,
    const uint16_t* __restrict__ x_h, const uint16_t* __restrict__ x_l,
    const float* __restrict__ xf,
    const uint16_t* __restrict__ wch_l, const uint16_t* __restrict__ wcl_l,
    const uint16_t* __restrict__ whhh, const uint16_t* __restrict__ whhl,
    const float* __restrict__ b_ih, const float* __restrict__ b_hh,
    float* __restrict__ out_f, uint16_t* __restrict__ out_h, uint16_t* __restrict__ out_l)
{
  int wave = threadIdx.x >> 6;
  int lane = threadIdx.x & 63;
  int mtile = blockIdx.x*4 + wave;
  if(mtile >= NN/16) return;          // 3125 M-tiles exactly
  int tcol = blockIdx.y;              // 0..5 (channel tile)
  int nidx = lane & 15;
  int quad = lane >> 4;

  size_t arow = (size_t)(mtile*16 + nidx)*CC;
  const uint16_t* sAh = s_h + arow;
  const uint16_t* sAl = s_l + arow;
  const uint16_t* xAh = x_h + arow;
  const uint16_t* xAl = x_l + arow;
  size_t bir = (size_t)(tcol     )*16*CC + nidx*CC;
  size_t biz = (size_t)(tcol + 6 )*16*CC + nidx*CC;
  size_t bin = (size_t)(tcol + 12)*16*CC + nidx*CC;

  f32x4 air = {0.f,0.f,0.f,0.f}, aiz = {0.f,0.f,0.f,0.f}, ain = {0.f,0.f,0.f,0.f};
  f32x4 ahr = {0.f,0.f,0.f,0.f}, ahz = {0.f,0.f,0.f,0.f}, ahn = {0.f,0.f,0.f,0.f};

  #pragma unroll
  for(int ks=0; ks<3; ks++){
    int ko = ks*32 + quad*8;
    bf16x8 ash = *reinterpret_cast<const bf16x8*>(sAh + ko);
    bf16x8 asl = *reinterpret_cast<const bf16x8*>(sAl + ko);
    bf16x8 axh = *reinterpret_cast<const bf16x8*>(xAh + ko);
    bf16x8 axl = *reinterpret_cast<const bf16x8*>(xAl + ko);
    bf16x8 bh, bl;

    bh = *reinterpret_cast<const bf16x8*>(wch_l + bir + ko);
    bl = *reinterpret_cast<const bf16x8*>(wcl_l + bir + ko);
    air = MFMA(ash, bh, air); air = MFMA(asl, bh, air); air = MFMA(ash, bl, air);
    bh = *reinterpret_cast<const bf16x8*>(wch_l + biz + ko);
    bl = *reinterpret_cast<const bf16x8*>(wcl_l + biz + ko);
    aiz = MFMA(ash, bh, aiz); aiz = MFMA(asl, bh, aiz); aiz = MFMA(ash, bl, aiz);
    bh = *reinterpret_cast<const bf16x8*>(wch_l + bin + ko);
    bl = *reinterpret_cast<const bf16x8*>(wcl_l + bin + ko);
    ain = MFMA(ash, bh, ain); ain = MFMA(asl, bh, ain); ain = MFMA(ash, bl, ain);

    bh = *reinterpret_cast<const bf16x8*>(whhh + bir + ko);
    bl = *reinterpret_cast<const bf16x8*>(whhl + bir + ko);
    ahr = MFMA(axh, bh, ahr); ahr = MFMA(axl, bh, ahr); ahr = MFMA(axh, bl, ahr);
    bh = *reinterpret_cast<const bf16x8*>(whhh + biz + ko);
    bl = *reinterpret_cast<const bf16x8*>(whhl + biz + ko);
    ahz = MFMA(axh, bh, ahz); ahz = MFMA(axl, bh, ahz); ahz = MFMA(axh, bl, ahz);
    bh = *reinterpret_cast<const bf16x8*>(whhh + bin + ko);
    bl = *reinterpret_cast<const bf16x8*>(whhl + bin + ko);
    ahn = MFMA(axh, bh, ahn); ahn = MFMA(axl, bh, ahn); ahn = MFMA(axh, bl, ahn);
  }

  int c = tcol*16 + nidx;
  float bir_ = b_ih[c], biz_ = b_ih[CC+c], bin_ = b_ih[2*CC+c];
  float bhr_ = b_hh[c], bhz_ = b_hh[CC+c], bhn_ = b_hh[2*CC+c];

  #pragma unroll
  for(int r=0;r<4;r++){
    int node = mtile*16 + quad*4 + r;   // C/D: row = quad*4 + reg, col = lane&15
    float ir  = air[r] + bir_;
    float iz  = aiz[r] + biz_;
    float in_ = ain[r] + bin_;
    float hr  = ahr[r] + bhr_;
    float hz  = ahz[r] + bhz_;
    float hn  = ahn[r] + bhn_;
    float rg = 1.f/(1.f + __expf(-(ir+hr)));
    float zg = 1.f/(1.f + __expf(-(iz+hz)));
    float nv = in_ + rg*hn;
    float av = fminf(fabsf(nv), 15.f);
    float e2 = __expf(2.f*av);
    float tg = 1.f - 2.f/(e2 + 1.f);
    tg = (nv < 0.f)? -tg : tg;
    float hp = xf[(size_t)node*CC + c];
    float h = (1.f - zg)*tg + zg*hp;
    size_t oi = (size_t)node*CC + c;
    out_f[oi] = h;
    if(out_h){
      uint16_t hh, hl; split_bf(h, hh, hl);
      out_h[oi] = hh; out_l[oi] = hl;
    }
  }
}

extern "C" void kernel_launch(void* const* d_in, const int* in_sizes, int n_in,
                              void* d_out, int out_size, void* d_ws, size_t ws_size,
                              hipStream_t stream){
  const float* x0     = (const float*)d_in[0];
  const int*   ei     = (const int*)d_in[1];
  const float* weight = (const float*)d_in[2];
  const float* w_ih   = (const float*)d_in[3];
  const float* w_hh   = (const float*)d_in[4];
  const float* b_ih   = (const float*)d_in[5];
  const float* b_hh   = (const float*)d_in[6];
  float* out = (float*)d_out;

  const int* srcv = ei;        // edge_index[0]
  const int* dstv = ei + NE;   // edge_index[1]

  char* ws = (char*)d_ws;
  size_t off = 0;
  auto carve = [&](size_t bytes)->char*{
    char* p = ws + off;
    off += (bytes + 255) & ~(size_t)255;
    return p;
  };
  int* counts   = (int*)carve((size_t)NN*4);
  int* offsets  = (int*)carve((size_t)NN*4);
  int* cursor   = (int*)carve((size_t)NN*4);
  int* gcur     = (int*)carve(4);
  int* ssrc     = (int*)carve((size_t)NE*4);
  uint16_t* s_h = (uint16_t*)carve((size_t)NN*CC*2);
  uint16_t* s_l = (uint16_t*)carve((size_t)NN*CC*2);
  uint16_t* xh0 = (uint16_t*)carve((size_t)NN*CC*2);
  uint16_t* xl0 = (uint16_t*)carve((size_t)NN*CC*2);
  uint16_t* xh1 = (uint16_t*)carve((size_t)NN*CC*2);
  uint16_t* xl1 = (uint16_t*)carve((size_t)NN*CC*2);
  float* xfA    = (float*)carve((size_t)NN*CC*4);     // f32 x after layer0/1 (in-place safe)
  uint16_t* wch  = (uint16_t*)carve((size_t)NL*18*16*CC*2);
  uint16_t* wcl  = (uint16_t*)carve((size_t)NL*18*16*CC*2);
  uint16_t* whhh = (uint16_t*)carve((size_t)18*16*CC*2);
  uint16_t* whhl = (uint16_t*)carve((size_t)18*16*CC*2);

  // CSR build (once — edge structure shared by all 3 layers). No serial scan:
  // bucket order is arbitrary, so wave-scan + global-cursor atomics assign ranges.
  k_zero<<<(NN+255)/256, 256, 0, stream>>>(counts, gcur);
  k_hist<<<(NE+255)/256, 256, 0, stream>>>(dstv, counts);
  k_assign<<<(NN+255)/256, 256, 0, stream>>>(counts, offsets, cursor, gcur);
  k_fill<<<(NE+255)/256, 256, 0, stream>>>(srcv, dstv, cursor, ssrc);

  // x0 -> hi/lo split; fold Wc = W @ w_ih^T and pack weights (hi/lo) once
  k_split<<<((NN*CC/4)+255)/256, 256, 0, stream>>>((const float4*)x0, (ushort4*)xh0, (ushort4*)xl0, NN*CC/4);
  k_pack_w<<<((NL*18*16*CC + 18*16*CC)+255)/256, 256, 0, stream>>>(weight, w_ih, w_hh, wch, wcl, whhh, whhl);

  const float* xf_cur = x0;
  uint16_t *xh_cur=xh0, *xl_cur=xl0, *xh_nxt=xh1, *xl_nxt=xl1;
  for(int l=0; l<NL; l++){
    k_aggregate<<<((NN*(CC/4))+255)/256, 256, 0, stream>>>(xf_cur, offsets, counts, ssrc, s_h, s_l);
    float* out_f = (l==NL-1) ? out : xfA;   // layer1 runs in-place on xfA (safe: 1:1 thread read->write)
    uint16_t* oh = (l==NL-1) ? nullptr : xh_nxt;
    uint16_t* ol = (l==NL-1) ? nullptr : xl_nxt;
    dim3 grid((NN/16 + 3)/4, 6);
    k_gru<<<grid, 256, 0, stream>>>(s_h, s_l, xh_cur, xl_cur, xf_cur,
                                    wch + (size_t)l*18*16*CC, wcl + (size_t)l*18*16*CC,
                                    whhh, whhl, b_ih, b_hh, out_f, oh, ol);
    xf_cur = out_f;
    uint16_t* t;
    t = xh_cur; xh_cur = xh_nxt; xh_nxt = t;
    t = xl_cur; xl_cur = xl_nxt; xl_nxt = t;
  }
}

// Round 4
// 515.883 us; speedup vs baseline: 1.6124x; 1.0688x over previous
//
#include <hip/hip_runtime.h>
#include <hip/hip_bf16.h>
#include <stdint.h>

#define NN 50000
#define NE 800000
#define CC 96
#define NL 3

typedef __bf16 bf16x8 __attribute__((ext_vector_type(8)));
typedef float f32x4 __attribute__((ext_vector_type(4)));

__device__ __forceinline__ uint16_t f2bf(float f){
  uint32_t u = __builtin_bit_cast(uint32_t, f);
  uint32_t r = (u + 0x7fffu + ((u >> 16) & 1u)) >> 16;
  return (uint16_t)r;
}
__device__ __forceinline__ float bf2f(uint16_t h){
  uint32_t u = ((uint32_t)h) << 16;
  return __builtin_bit_cast(float, u);
}
// split f32 -> (hi, lo) bf16 pair; hi+lo reproduces f ~17 mantissa bits
__device__ __forceinline__ void split_bf(float f, uint16_t& hi, uint16_t& lo){
  hi = f2bf(f);
  lo = f2bf(f - bf2f(hi));
}
// load 8 contiguous f32 and split to hi/lo bf16x8 fragments (in-register)
__device__ __forceinline__ void split8(const float* p, bf16x8& h8, bf16x8& l8){
  float4 a = *(const float4*)p;
  float4 b = *(const float4*)(p+4);
  float v[8] = {a.x,a.y,a.z,a.w,b.x,b.y,b.z,b.w};
  #pragma unroll
  for(int j=0;j<8;j++){
    uint16_t hi, lo; split_bf(v[j], hi, lo);
    h8[j] = __builtin_bit_cast(__bf16, hi);
    l8[j] = __builtin_bit_cast(__bf16, lo);
  }
}

__global__ void k_zero(int* counts, int* gcur){
  int i = blockIdx.x*256 + threadIdx.x;
  if(i < NN) counts[i] = 0;
  if(i == 0) *gcur = 0;
}

__global__ void k_hist(const int* __restrict__ dstv, int* __restrict__ counts){
  int e = blockIdx.x*256 + threadIdx.x;
  if(e < NE) atomicAdd(&counts[dstv[e]], 1);
}

// Scan-free bucket assignment: CSR bucket ORDER is arbitrary — wave-prefix-scan
// counts, one atomicAdd on a global cursor per wave grabs the bucket range.
__global__ void k_assign(const int* __restrict__ counts, int* __restrict__ offsets,
                         int* __restrict__ cursor, int* __restrict__ gcur){
  int i = blockIdx.x*256 + threadIdx.x;
  int lane = threadIdx.x & 63;
  int v = (i < NN) ? counts[i] : 0;
  int sum = v;                          // inclusive wave scan
  #pragma unroll
  for(int d=1; d<64; d<<=1){
    int t = __shfl_up(sum, d, 64);
    if(lane >= d) sum += t;
  }
  int total = __shfl(sum, 63, 64);
  int base = 0;
  if(lane == 63) base = atomicAdd(gcur, total);
  base = __shfl(base, 63, 64);
  int off = base + sum - v;
  if(i < NN){ offsets[i] = off; cursor[i] = off; }
}

__global__ void k_fill(const int* __restrict__ srcv, const int* __restrict__ dstv,
                       int* __restrict__ cursor, int* __restrict__ ssrc){
  int e = blockIdx.x*256 + threadIdx.x;
  if(e < NE){
    int d = dstv[e];
    int pos = atomicAdd(&cursor[d], 1);
    ssrc[pos] = srcv[e];
  }
}

// Pack Wc[l] = weight[l] @ w_ih^T into [l][tile18][n16][k96] hi/lo bf16,
// and w_hh^T into [tile18][n16][k96] hi/lo bf16. float4 dot (rows are 384B-aligned).
__global__ void k_pack_w(const float* __restrict__ weight, const float* __restrict__ w_ih,
                         const float* __restrict__ w_hh,
                         uint16_t* __restrict__ wch, uint16_t* __restrict__ wcl,
                         uint16_t* __restrict__ whhh, uint16_t* __restrict__ whhl){
  int idx = blockIdx.x*256 + threadIdx.x;
  const int TOT1 = NL*18*16*CC;   // 82944
  const int TOT2 = 18*16*CC;      // 27648
  if(idx < TOT1){
    int k = idx % CC;
    int n = (idx / CC) & 15;
    int t = (idx / (CC*16)) % 18;
    int l = idx / (CC*16*18);
    int j = t*16 + n;             // output column in [0,288)
    const float4* wr = (const float4*)(weight + (size_t)(l*CC + k)*CC);
    const float4* ir = (const float4*)(w_ih + (size_t)j*CC);
    float acc = 0.f;
    #pragma unroll 4
    for(int k2=0;k2<CC/4;k2++){
      float4 a = wr[k2], b = ir[k2];
      acc += a.x*b.x + a.y*b.y + a.z*b.z + a.w*b.w;
    }
    uint16_t h, lo; split_bf(acc, h, lo);
    wch[idx] = h; wcl[idx] = lo;
  } else {
    int idx2 = idx - TOT1;
    if(idx2 < TOT2){
      int k = idx2 % CC;
      int n = (idx2 / CC) & 15;
      int t = idx2 / (CC*16);
      int j = t*16 + n;
      uint16_t h, lo; split_bf(w_hh[(size_t)j*CC + k], h, lo);
      whhh[idx2] = h; whhl[idx2] = lo;
    }
  }
}

// CSR aggregation, f32 in/out: thread = (node, c4), float4 gathers,
// 8-wide ssrc prefetch for memory-level parallelism.
__global__ void k_aggregate(const float* __restrict__ xf, const int* __restrict__ offsets,
                            const int* __restrict__ counts, const int* __restrict__ ssrc,
                            float* __restrict__ s_f){
  int tid = blockIdx.x*256 + threadIdx.x;
  if(tid >= NN*(CC/4)) return;
  int n = tid / (CC/4);
  int c4 = tid - n*(CC/4);
  int o0 = offsets[n];
  int o1 = o0 + counts[n];
  const float4* xf4 = (const float4*)xf;
  float ax=0.f, ay=0.f, az=0.f, aw=0.f;
  int j = o0;
  for(; j+8 <= o1; j+=8){
    int s0 = ssrc[j],   s1 = ssrc[j+1], s2 = ssrc[j+2], s3 = ssrc[j+3];
    int s4 = ssrc[j+4], s5 = ssrc[j+5], s6 = ssrc[j+6], s7 = ssrc[j+7];
    float4 v0 = xf4[(size_t)s0*(CC/4) + c4];
    float4 v1 = xf4[(size_t)s1*(CC/4) + c4];
    float4 v2 = xf4[(size_t)s2*(CC/4) + c4];
    float4 v3 = xf4[(size_t)s3*(CC/4) + c4];
    float4 v4 = xf4[(size_t)s4*(CC/4) + c4];
    float4 v5 = xf4[(size_t)s5*(CC/4) + c4];
    float4 v6 = xf4[(size_t)s6*(CC/4) + c4];
    float4 v7 = xf4[(size_t)s7*(CC/4) + c4];
    ax += (v0.x+v1.x)+(v2.x+v3.x)+((v4.x+v5.x)+(v6.x+v7.x));
    ay += (v0.y+v1.y)+(v2.y+v3.y)+((v4.y+v5.y)+(v6.y+v7.y));
    az += (v0.z+v1.z)+(v2.z+v3.z)+((v4.z+v5.z)+(v6.z+v7.z));
    aw += (v0.w+v1.w)+(v2.w+v3.w)+((v4.w+v5.w)+(v6.w+v7.w));
  }
  for(; j < o1; j++){
    float4 v = xf4[(size_t)ssrc[j]*(CC/4) + c4];
    ax += v.x; ay += v.y; az += v.z; aw += v.w;
  }
  float4 o; o.x=ax; o.y=ay; o.z=az; o.w=aw;
  ((float4*)s_f)[tid] = o;
}

#define MFMA(A,B,C) __builtin_amdgcn_mfma_f32_16x16x32_bf16(A,B,C,0,0,0)

// Fused dual-GEMM (gi = s@Wc, gh = x@WhhT) in split-bf16 (3 MFMA/gate/K-step)
// + GRU epilogue. 1 wave = 16 nodes x ALL 96 channels: A fragments stay in
// registers across the 6 channel-tiles (6x less operand traffic than grid-y).
__global__ __launch_bounds__(256) void k_gru(
    const float* __restrict__ s_f, const float* __restrict__ xf,
    const uint16_t* __restrict__ wch_l, const uint16_t* __restrict__ wcl_l,
    const uint16_t* __restrict__ whhh, const uint16_t* __restrict__ whhl,
    const float* __restrict__ b_ih, const float* __restrict__ b_hh,
    float* __restrict__ out_f)
{
  int wave = threadIdx.x >> 6;
  int lane = threadIdx.x & 63;
  int mtile = blockIdx.x*4 + wave;
  if(mtile >= NN/16) return;          // 3125 M-tiles exactly
  int nidx = lane & 15;
  int quad = lane >> 4;

  size_t arow = (size_t)(mtile*16 + nidx)*CC;
  // Load + split A fragments for all 3 K-steps, keep resident (48 VGPRs)
  bf16x8 ash[3], asl[3], axh[3], axl[3];
  #pragma unroll
  for(int ks=0; ks<3; ks++){
    int ko = ks*32 + quad*8;
    split8(s_f + arow + ko, ash[ks], asl[ks]);
    split8(xf  + arow + ko, axh[ks], axl[ks]);
  }

  #pragma unroll 1
  for(int tcol=0; tcol<6; tcol++){
    size_t bir = (size_t)(tcol     )*16*CC + nidx*CC;
    size_t biz = (size_t)(tcol + 6 )*16*CC + nidx*CC;
    size_t bin = (size_t)(tcol + 12)*16*CC + nidx*CC;

    f32x4 air = {0.f,0.f,0.f,0.f}, aiz = {0.f,0.f,0.f,0.f}, ain = {0.f,0.f,0.f,0.f};
    f32x4 ahr = {0.f,0.f,0.f,0.f}, ahz = {0.f,0.f,0.f,0.f}, ahn = {0.f,0.f,0.f,0.f};

    #pragma unroll
    for(int ks=0; ks<3; ks++){
      int ko = ks*32 + quad*8;
      bf16x8 bh, bl;
      bh = *reinterpret_cast<const bf16x8*>(wch_l + bir + ko);
      bl = *reinterpret_cast<const bf16x8*>(wcl_l + bir + ko);
      air = MFMA(ash[ks], bh, air); air = MFMA(asl[ks], bh, air); air = MFMA(ash[ks], bl, air);
      bh = *reinterpret_cast<const bf16x8*>(wch_l + biz + ko);
      bl = *reinterpret_cast<const bf16x8*>(wcl_l + biz + ko);
      aiz = MFMA(ash[ks], bh, aiz); aiz = MFMA(asl[ks], bh, aiz); aiz = MFMA(ash[ks], bl, aiz);
      bh = *reinterpret_cast<const bf16x8*>(wch_l + bin + ko);
      bl = *reinterpret_cast<const bf16x8*>(wcl_l + bin + ko);
      ain = MFMA(ash[ks], bh, ain); ain = MFMA(asl[ks], bh, ain); ain = MFMA(ash[ks], bl, ain);

      bh = *reinterpret_cast<const bf16x8*>(whhh + bir + ko);
      bl = *reinterpret_cast<const bf16x8*>(whhl + bir + ko);
      ahr = MFMA(axh[ks], bh, ahr); ahr = MFMA(axl[ks], bh, ahr); ahr = MFMA(axh[ks], bl, ahr);
      bh = *reinterpret_cast<const bf16x8*>(whhh + biz + ko);
      bl = *reinterpret_cast<const bf16x8*>(whhl + biz + ko);
      ahz = MFMA(axh[ks], bh, ahz); ahz = MFMA(axl[ks], bh, ahz); ahz = MFMA(axh[ks], bl, ahz);
      bh = *reinterpret_cast<const bf16x8*>(whhh + bin + ko);
      bl = *reinterpret_cast<const bf16x8*>(whhl + bin + ko);
      ahn = MFMA(axh[ks], bh, ahn); ahn = MFMA(axl[ks], bh, ahn); ahn = MFMA(axh[ks], bl, ahn);
    }

    int c = tcol*16 + nidx;
    float bir_ = b_ih[c], biz_ = b_ih[CC+c], bin_ = b_ih[2*CC+c];
    float bhr_ = b_hh[c], bhz_ = b_hh[CC+c], bhn_ = b_hh[2*CC+c];

    #pragma unroll
    for(int r=0;r<4;r++){
      int node = mtile*16 + quad*4 + r;   // C/D: row = quad*4 + reg, col = lane&15
      float ir  = air[r] + bir_;
      float iz  = aiz[r] + biz_;
      float in_ = ain[r] + bin_;
      float hr  = ahr[r] + bhr_;
      float hz  = ahz[r] + bhz_;
      float hn  = ahn[r] + bhn_;
      float rg = 1.f/(1.f + __expf(-(ir+hr)));
      float zg = 1.f/(1.f + __expf(-(iz+hz)));
      float nv = in_ + rg*hn;
      float av = fminf(fabsf(nv), 15.f);
      float e2 = __expf(2.f*av);
      float tg = 1.f - 2.f/(e2 + 1.f);
      tg = (nv < 0.f)? -tg : tg;
      float hp = xf[(size_t)node*CC + c];
      float h = (1.f - zg)*tg + zg*hp;
      out_f[(size_t)node*CC + c] = h;
    }
  }
}

extern "C" void kernel_launch(void* const* d_in, const int* in_sizes, int n_in,
                              void* d_out, int out_size, void* d_ws, size_t ws_size,
                              hipStream_t stream){
  const float* x0     = (const float*)d_in[0];
  const int*   ei     = (const int*)d_in[1];
  const float* weight = (const float*)d_in[2];
  const float* w_ih   = (const float*)d_in[3];
  const float* w_hh   = (const float*)d_in[4];
  const float* b_ih   = (const float*)d_in[5];
  const float* b_hh   = (const float*)d_in[6];
  float* out = (float*)d_out;

  const int* srcv = ei;        // edge_index[0]
  const int* dstv = ei + NE;   // edge_index[1]

  char* ws = (char*)d_ws;
  size_t off = 0;
  auto carve = [&](size_t bytes)->char*{
    char* p = ws + off;
    off += (bytes + 255) & ~(size_t)255;
    return p;
  };
  int* counts   = (int*)carve((size_t)NN*4);
  int* offsets  = (int*)carve((size_t)NN*4);
  int* cursor   = (int*)carve((size_t)NN*4);
  int* gcur     = (int*)carve(4);
  int* ssrc     = (int*)carve((size_t)NE*4);
  float* s_f    = (float*)carve((size_t)NN*CC*4);
  float* xfA    = (float*)carve((size_t)NN*CC*4);     // f32 x after layer0/1 (in-place safe)
  uint16_t* wch  = (uint16_t*)carve((size_t)NL*18*16*CC*2);
  uint16_t* wcl  = (uint16_t*)carve((size_t)NL*18*16*CC*2);
  uint16_t* whhh = (uint16_t*)carve((size_t)18*16*CC*2);
  uint16_t* whhl = (uint16_t*)carve((size_t)18*16*CC*2);

  // CSR build (once — edge structure shared by all 3 layers). No serial scan:
  // bucket order is arbitrary, so wave-scan + global-cursor atomics assign ranges.
  k_zero<<<(NN+255)/256, 256, 0, stream>>>(counts, gcur);
  k_hist<<<(NE+255)/256, 256, 0, stream>>>(dstv, counts);
  k_assign<<<(NN+255)/256, 256, 0, stream>>>(counts, offsets, cursor, gcur);
  k_fill<<<(NE+255)/256, 256, 0, stream>>>(srcv, dstv, cursor, ssrc);

  // Fold Wc = W @ w_ih^T and pack weights (hi/lo) once
  k_pack_w<<<((NL*18*16*CC + 18*16*CC)+255)/256, 256, 0, stream>>>(weight, w_ih, w_hh, wch, wcl, whhh, whhl);

  const float* xf_cur = x0;
  for(int l=0; l<NL; l++){
    k_aggregate<<<((NN*(CC/4))+255)/256, 256, 0, stream>>>(xf_cur, offsets, counts, ssrc, s_f);
    float* out_f = (l==NL-1) ? out : xfA;   // layer1 in-place on xfA (safe: each row read/written only by its own wave, reads precede writes)
    k_gru<<<(NN/16 + 3)/4, 256, 0, stream>>>(s_f, xf_cur,
                                    wch + (size_t)l*18*16*CC, wcl + (size_t)l*18*16*CC,
                                    whhh, whhl, b_ih, b_hh, out_f);
    xf_cur = out_f;
  }
}

// Round 5
// 434.913 us; speedup vs baseline: 1.9126x; 1.1862x over previous
//
#include <hip/hip_runtime.h>
#include <hip/hip_bf16.h>
#include <stdint.h>

#define NN 50000
#define NE 800000
#define CC 96
#define NL 3

// packed-weight geometry: per layer, per tcol: 9 frag-sets (part*3+gate) x 3 ks x 64 lanes x 8 bf16
#define FRAGS_PER_TCOL 1728              // 9*3*64
#define ELEMS_PER_TCOL 13824             // FRAGS*8
#define ELEMS_PER_LAYER 82944            // 6*ELEMS_PER_TCOL

typedef __bf16 bf16x8 __attribute__((ext_vector_type(8)));
typedef float f32x4 __attribute__((ext_vector_type(4)));

__device__ __forceinline__ uint16_t f2bf(float f){
  uint32_t u = __builtin_bit_cast(uint32_t, f);
  uint32_t r = (u + 0x7fffu + ((u >> 16) & 1u)) >> 16;
  return (uint16_t)r;
}
__device__ __forceinline__ float bf2f(uint16_t h){
  uint32_t u = ((uint32_t)h) << 16;
  return __builtin_bit_cast(float, u);
}
__device__ __forceinline__ void split_bf(float f, uint16_t& hi, uint16_t& lo){
  hi = f2bf(f);
  lo = f2bf(f - bf2f(hi));
}
// load 8 contiguous f32 and split to hi/lo bf16x8 fragments (in-register)
__device__ __forceinline__ void split8(const float* p, bf16x8& h8, bf16x8& l8){
  float4 a = *(const float4*)p;
  float4 b = *(const float4*)(p+4);
  float v[8] = {a.x,a.y,a.z,a.w,b.x,b.y,b.z,b.w};
  #pragma unroll
  for(int j=0;j<8;j++){
    uint16_t hi, lo; split_bf(v[j], hi, lo);
    h8[j] = __builtin_bit_cast(__bf16, hi);
    l8[j] = __builtin_bit_cast(__bf16, lo);
  }
}

__global__ void k_zero(int* counts, int* gcur){
  int i = blockIdx.x*256 + threadIdx.x;
  if(i < NN) counts[i] = 0;
  if(i == 0) *gcur = 0;
}

__global__ void k_hist(const int* __restrict__ dstv, int* __restrict__ counts){
  int e = blockIdx.x*256 + threadIdx.x;
  if(e < NE) atomicAdd(&counts[dstv[e]], 1);
}

// Scan-free bucket assignment: CSR bucket ORDER is arbitrary — wave-prefix-scan
// counts, one atomicAdd on a global cursor per wave grabs the bucket range.
__global__ void k_assign(const int* __restrict__ counts, int* __restrict__ offsets,
                         int* __restrict__ cursor, int* __restrict__ gcur){
  int i = blockIdx.x*256 + threadIdx.x;
  int lane = threadIdx.x & 63;
  int v = (i < NN) ? counts[i] : 0;
  int sum = v;
  #pragma unroll
  for(int d=1; d<64; d<<=1){
    int t = __shfl_up(sum, d, 64);
    if(lane >= d) sum += t;
  }
  int total = __shfl(sum, 63, 64);
  int base = 0;
  if(lane == 63) base = atomicAdd(gcur, total);
  base = __shfl(base, 63, 64);
  int off = base + sum - v;
  if(i < NN){ offsets[i] = off; cursor[i] = off; }
}

__global__ void k_fill(const int* __restrict__ srcv, const int* __restrict__ dstv,
                       int* __restrict__ cursor, int* __restrict__ ssrc){
  int e = blockIdx.x*256 + threadIdx.x;
  if(e < NE){
    int d = dstv[e];
    int pos = atomicAdd(&cursor[d], 1);
    ssrc[pos] = srcv[e];
  }
}

// Pack weights in MFMA-fragment-linear order.
// gw[l][tcol][pg][ks][lane][8] where pg = part*3+gate; part 0=Wc_hi, 1=Wc_lo, 2=Whh(hi only).
// Fragment mapping (B operand of 16x16x32): n = lane&15, k = (lane>>4)*8 + j.
// Wc[col][k] = dot(weight[l][:, col? ]...)  Wc = weight[l] @ w_ih^T, col in [0,288), k in [0,96).
__device__ __forceinline__ size_t frag_elem(int tcol, int part, int g, int ks, int lane, int j){
  return ((size_t)((tcol*9 + part*3 + g)*3 + ks)*64 + lane)*8 + j;
}
__global__ void k_pack_w(const float* __restrict__ weight, const float* __restrict__ w_ih,
                         const float* __restrict__ w_hh, uint16_t* __restrict__ gw){
  int idx = blockIdx.x*256 + threadIdx.x;
  const int TOT1 = NL*288*CC;     // Wc threads: (l, col, k)
  const int TOT2 = 288*CC;        // Whh threads: (col, k) -> write all 3 layers
  if(idx < TOT1){
    int k = idx % CC;
    int col = (idx / CC) % 288;
    int l = idx / (CC*288);
    // Wc[col][k] = sum_k2 weight[l][k][k2]... careful: m = x @ W, gi = s @ Wc with
    // Wc[k][col] = sum_k2 W[k][k2] * w_ih[col][k2]; B-frag needs Wc[col-th output][k]:
    const float4* wr = (const float4*)(weight + (size_t)(l*CC + k)*CC);
    const float4* ir = (const float4*)(w_ih + (size_t)col*CC);
    float acc = 0.f;
    #pragma unroll 4
    for(int k2=0;k2<CC/4;k2++){
      float4 a = wr[k2], b = ir[k2];
      acc += a.x*b.x + a.y*b.y + a.z*b.z + a.w*b.w;
    }
    uint16_t h, lo; split_bf(acc, h, lo);
    int g = col / 96, cg = col % 96;
    int tcol = cg >> 4, n = cg & 15;
    int ks = k >> 5, r = (k & 31) >> 3, j = k & 7;
    int lane = r*16 + n;
    size_t lb = (size_t)l*ELEMS_PER_LAYER;
    gw[lb + frag_elem(tcol, 0, g, ks, lane, j)] = h;
    gw[lb + frag_elem(tcol, 1, g, ks, lane, j)] = lo;
  } else {
    int idx2 = idx - TOT1;
    if(idx2 < TOT2){
      int k = idx2 % CC;
      int col = idx2 / CC;
      uint16_t h = f2bf(w_hh[(size_t)col*CC + k]);
      int g = col / 96, cg = col % 96;
      int tcol = cg >> 4, n = cg & 15;
      int ks = k >> 5, r = (k & 31) >> 3, j = k & 7;
      int lane = r*16 + n;
      size_t fe = frag_elem(tcol, 2, g, ks, lane, j);
      #pragma unroll
      for(int l=0;l<NL;l++) gw[(size_t)l*ELEMS_PER_LAYER + fe] = h;
    }
  }
}

// CSR aggregation, f32 in/out: thread = (node, c4), float4 gathers,
// 8-wide ssrc prefetch for memory-level parallelism.
__global__ void k_aggregate(const float* __restrict__ xf, const int* __restrict__ offsets,
                            const int* __restrict__ counts, const int* __restrict__ ssrc,
                            float* __restrict__ s_f){
  int tid = blockIdx.x*256 + threadIdx.x;
  if(tid >= NN*(CC/4)) return;
  int n = tid / (CC/4);
  int c4 = tid - n*(CC/4);
  int o0 = offsets[n];
  int o1 = o0 + counts[n];
  const float4* xf4 = (const float4*)xf;
  float ax=0.f, ay=0.f, az=0.f, aw=0.f;
  int j = o0;
  for(; j+8 <= o1; j+=8){
    int s0 = ssrc[j],   s1 = ssrc[j+1], s2 = ssrc[j+2], s3 = ssrc[j+3];
    int s4 = ssrc[j+4], s5 = ssrc[j+5], s6 = ssrc[j+6], s7 = ssrc[j+7];
    float4 v0 = xf4[(size_t)s0*(CC/4) + c4];
    float4 v1 = xf4[(size_t)s1*(CC/4) + c4];
    float4 v2 = xf4[(size_t)s2*(CC/4) + c4];
    float4 v3 = xf4[(size_t)s3*(CC/4) + c4];
    float4 v4 = xf4[(size_t)s4*(CC/4) + c4];
    float4 v5 = xf4[(size_t)s5*(CC/4) + c4];
    float4 v6 = xf4[(size_t)s6*(CC/4) + c4];
    float4 v7 = xf4[(size_t)s7*(CC/4) + c4];
    ax += (v0.x+v1.x)+(v2.x+v3.x)+((v4.x+v5.x)+(v6.x+v7.x));
    ay += (v0.y+v1.y)+(v2.y+v3.y)+((v4.y+v5.y)+(v6.y+v7.y));
    az += (v0.z+v1.z)+(v2.z+v3.z)+((v4.z+v5.z)+(v6.z+v7.z));
    aw += (v0.w+v1.w)+(v2.w+v3.w)+((v4.w+v5.w)+(v6.w+v7.w));
  }
  for(; j < o1; j++){
    float4 v = xf4[(size_t)ssrc[j]*(CC/4) + c4];
    ax += v.x; ay += v.y; az += v.z; aw += v.w;
  }
  float4 o; o.x=ax; o.y=ay; o.z=az; o.w=aw;
  ((float4*)s_f)[tid] = o;
}

#define MFMA(A,B,C) __builtin_amdgcn_mfma_f32_16x16x32_bf16(A,B,C,0,0,0)

// Fused dual-GEMM + GRU. Per tcol, the 27KB fragment-packed weight slab is staged
// into LDS once per block (coalesced), then read via conflict-free ds_read_b128 —
// no per-wave divergent global B-loads (the R4 bottleneck).
// gi = sh*Bh + sl*Bh + sh*Bl (Wc hi/lo); gh = xh*Bh + xl*Bh (Whh hi only).
__global__ __launch_bounds__(256) void k_gru(
    const float* __restrict__ s_f, const float* __restrict__ xf,
    const uint16_t* __restrict__ gw_l,
    const float* __restrict__ b_ih, const float* __restrict__ b_hh,
    float* __restrict__ out_f)
{
  __shared__ __align__(16) uint16_t lw[ELEMS_PER_TCOL];   // 27648 B

  int wave = threadIdx.x >> 6;
  int lane = threadIdx.x & 63;
  int mtile = blockIdx.x*4 + wave;
  bool valid = (mtile < NN/16);
  int mt = valid ? mtile : (NN/16 - 1);   // clamp; no early return (barrier safety)
  int nidx = lane & 15;
  int quad = lane >> 4;

  size_t arow = (size_t)(mt*16 + nidx)*CC;
  bf16x8 ash[3], asl[3], axh[3], axl[3];
  #pragma unroll
  for(int ks=0; ks<3; ks++){
    int ko = ks*32 + quad*8;
    split8(s_f + arow + ko, ash[ks], asl[ks]);
    split8(xf  + arow + ko, axh[ks], axl[ks]);
  }

  #pragma unroll 1
  for(int tcol=0; tcol<6; tcol++){
    if(tcol > 0) __syncthreads();        // prior tcol's LDS reads complete
    // stage 27KB: 1728 x 16B chunks, 256 threads -> 7 iterations
    {
      const uint4* src = (const uint4*)(gw_l + (size_t)tcol*ELEMS_PER_TCOL);
      uint4* dst = (uint4*)lw;
      #pragma unroll
      for(int i=0;i<7;i++){
        int chunk = i*256 + threadIdx.x;
        if(chunk < FRAGS_PER_TCOL) dst[chunk] = src[chunk];
      }
    }
    __syncthreads();

    f32x4 air = {0.f,0.f,0.f,0.f}, aiz = {0.f,0.f,0.f,0.f}, ain = {0.f,0.f,0.f,0.f};
    f32x4 ahr = {0.f,0.f,0.f,0.f}, ahz = {0.f,0.f,0.f,0.f}, ahn = {0.f,0.f,0.f,0.f};

    #pragma unroll
    for(int ks=0; ks<3; ks++){
      // frag offset: ((pg*3+ks)*64+lane)*8 elems; pg = part*3+gate
      const uint16_t* base = lw + ((size_t)ks*64 + lane)*8;
      #define BFRAG(part,g) (*reinterpret_cast<const bf16x8*>(base + (size_t)((part)*3+(g))*3*64*8))
      bf16x8 b;
      b = BFRAG(0,0); air = MFMA(ash[ks], b, air); air = MFMA(asl[ks], b, air);
      b = BFRAG(1,0); air = MFMA(ash[ks], b, air);
      b = BFRAG(0,1); aiz = MFMA(ash[ks], b, aiz); aiz = MFMA(asl[ks], b, aiz);
      b = BFRAG(1,1); aiz = MFMA(ash[ks], b, aiz);
      b = BFRAG(0,2); ain = MFMA(ash[ks], b, ain); ain = MFMA(asl[ks], b, ain);
      b = BFRAG(1,2); ain = MFMA(ash[ks], b, ain);
      b = BFRAG(2,0); ahr = MFMA(axh[ks], b, ahr); ahr = MFMA(axl[ks], b, ahr);
      b = BFRAG(2,1); ahz = MFMA(axh[ks], b, ahz); ahz = MFMA(axl[ks], b, ahz);
      b = BFRAG(2,2); ahn = MFMA(axh[ks], b, ahn); ahn = MFMA(axl[ks], b, ahn);
      #undef BFRAG
    }

    int c = tcol*16 + nidx;
    float bir_ = b_ih[c], biz_ = b_ih[CC+c], bin_ = b_ih[2*CC+c];
    float bhr_ = b_hh[c], bhz_ = b_hh[CC+c], bhn_ = b_hh[2*CC+c];

    #pragma unroll
    for(int r=0;r<4;r++){
      int node = mt*16 + quad*4 + r;     // C/D: row = quad*4 + reg, col = lane&15
      float ir  = air[r] + bir_;
      float iz  = aiz[r] + biz_;
      float in_ = ain[r] + bin_;
      float hr  = ahr[r] + bhr_;
      float hz  = ahz[r] + bhz_;
      float hn  = ahn[r] + bhn_;
      float rg = 1.f/(1.f + __expf(-(ir+hr)));
      float zg = 1.f/(1.f + __expf(-(iz+hz)));
      float nv = in_ + rg*hn;
      float av = fminf(fabsf(nv), 15.f);
      float e2 = __expf(2.f*av);
      float tg = 1.f - 2.f/(e2 + 1.f);
      tg = (nv < 0.f)? -tg : tg;
      float hp = xf[(size_t)node*CC + c];
      float h = (1.f - zg)*tg + zg*hp;
      if(valid) out_f[(size_t)node*CC + c] = h;
    }
  }
}

extern "C" void kernel_launch(void* const* d_in, const int* in_sizes, int n_in,
                              void* d_out, int out_size, void* d_ws, size_t ws_size,
                              hipStream_t stream){
  const float* x0     = (const float*)d_in[0];
  const int*   ei     = (const int*)d_in[1];
  const float* weight = (const float*)d_in[2];
  const float* w_ih   = (const float*)d_in[3];
  const float* w_hh   = (const float*)d_in[4];
  const float* b_ih   = (const float*)d_in[5];
  const float* b_hh   = (const float*)d_in[6];
  float* out = (float*)d_out;

  const int* srcv = ei;        // edge_index[0]
  const int* dstv = ei + NE;   // edge_index[1]

  char* ws = (char*)d_ws;
  size_t off = 0;
  auto carve = [&](size_t bytes)->char*{
    char* p = ws + off;
    off += (bytes + 255) & ~(size_t)255;
    return p;
  };
  int* counts   = (int*)carve((size_t)NN*4);
  int* offsets  = (int*)carve((size_t)NN*4);
  int* cursor   = (int*)carve((size_t)NN*4);
  int* gcur     = (int*)carve(4);
  int* ssrc     = (int*)carve((size_t)NE*4);
  float* s_f    = (float*)carve((size_t)NN*CC*4);
  float* xfA    = (float*)carve((size_t)NN*CC*4);
  uint16_t* gw  = (uint16_t*)carve((size_t)NL*ELEMS_PER_LAYER*2);

  // CSR build (once — edge structure shared by all 3 layers)
  k_zero<<<(NN+255)/256, 256, 0, stream>>>(counts, gcur);
  k_hist<<<(NE+255)/256, 256, 0, stream>>>(dstv, counts);
  k_assign<<<(NN+255)/256, 256, 0, stream>>>(counts, offsets, cursor, gcur);
  k_fill<<<(NE+255)/256, 256, 0, stream>>>(srcv, dstv, cursor, ssrc);

  // Fold Wc = W @ w_ih^T, pack all weights fragment-linear (hi/lo for Wc, hi for Whh)
  k_pack_w<<<((NL*288*CC + 288*CC)+255)/256, 256, 0, stream>>>(weight, w_ih, w_hh, gw);

  const float* xf_cur = x0;
  for(int l=0; l<NL; l++){
    k_aggregate<<<((NN*(CC/4))+255)/256, 256, 0, stream>>>(xf_cur, offsets, counts, ssrc, s_f);
    float* out_f = (l==NL-1) ? out : xfA;   // layer1 in-place on xfA: waves own disjoint rows, reads precede writes per channel-tile
    k_gru<<<(NN/16 + 3)/4, 256, 0, stream>>>(s_f, xf_cur, gw + (size_t)l*ELEMS_PER_LAYER,
                                             b_ih, b_hh, out_f);
    xf_cur = out_f;
  }
}